// Round 10
// baseline (247.446 us; speedup 1.0000x reference)
//
#include <hip/hip_runtime.h>
#include <stdint.h>

// TransformerBlock on MI355X (gfx950), bf16-MFMA. Round 10.
// vs R9: flash_attn QBLK 64->128 — 32 Q-rows per wave (2 groups of 16), so each
// K/V fragment LDS read feeds 2 MFMAs (halves LDS bytes per Q-row; flash was
// LDS-BW-bound: ~210KB/iter/CU at ~85B/cyc ~= the observed 3900 cyc/iter).
// Grid 256 blocks (1/CU). GEMM/cast/LN/transpose unchanged from R9.

#define NTOK 2048
#define DMODEL 1024
#define NHEAD 16
#define DHEAD 64
#define DFF 4096

typedef __attribute__((ext_vector_type(8))) short short8;
typedef __attribute__((ext_vector_type(4))) short short4v;
typedef __attribute__((ext_vector_type(4))) float f32x4;

__device__ __forceinline__ float fexp2(float x) { return __builtin_amdgcn_exp2f(x); }

// fp32 -> bf16 RNE
__device__ __forceinline__ short f2b(float f) {
  union { float f; unsigned u; } v; v.f = f;
  unsigned r = v.u + 0x7fffu + ((v.u >> 16) & 1u);
  return (short)(r >> 16);
}

__device__ __forceinline__ void gload_lds16(const void* g, void* l) {
  __builtin_amdgcn_global_load_lds((const __attribute__((address_space(1))) void*)g,
                                   (__attribute__((address_space(3))) void*)l,
                                   16, 0, 0);
}

// ---------------- fused cast fp32 -> bf16 for 4 tensors ----------------
__global__ void cast_all(const float* __restrict__ s0, short* __restrict__ d0, int n0,
                         const float* __restrict__ s1, short* __restrict__ d1, int n1,
                         const float* __restrict__ s2, short* __restrict__ d2, int n2,
                         const float* __restrict__ s3, short* __restrict__ d3, int n3) {
  int i = blockIdx.x * blockDim.x + threadIdx.x;
  const float* s; short* d; int j = i;
  if (j < n0) { s = s0; d = d0; }
  else { j -= n0;
    if (j < n1) { s = s1; d = d1; }
    else { j -= n1;
      if (j < n2) { s = s2; d = d2; }
      else { j -= n2; if (j >= n3) return; s = s3; d = d3; }
    }
  }
  const float4* p = (const float4*)(s + (size_t)j * 8);
  float4 a = p[0], b = p[1];
  short8 o;
  o[0] = f2b(a.x); o[1] = f2b(a.y); o[2] = f2b(a.z); o[3] = f2b(a.w);
  o[4] = f2b(b.x); o[5] = f2b(b.y); o[6] = f2b(b.z); o[7] = f2b(b.w);
  *(short8*)(d + (size_t)j * 8) = o;
}

// ---------------- GEMM: C = A @ B^T (+relu/bias), bf16 in, f32 acc (R9) ----------------
template<int BM, int BN, int WR, int WC, bool BF16OUT, bool BIAS, bool RELU>
__launch_bounds__(WR * WC * 64, 2)
__global__ void gemm_bt(const short* __restrict__ A, const short* __restrict__ B,
                        const float* __restrict__ bias,
                        float* __restrict__ Cf, short* __restrict__ Cb,
                        int M, int N, int K, int lda, int ldb, int kstep) {
  constexpr int BK = 64;
  constexpr int THREADS = WR * WC * 64;
  constexpr int ACH = (BM * (BK / 8)) / THREADS;
  constexpr int BCH = (BN * (BK / 8)) / THREADS;
  constexpr int LPS = ACH + BCH;
  constexpr int MR = BM / (WR * 16);
  constexpr int NR = BN / (WC * 16);
  __shared__ short As[3][BM * BK];
  __shared__ short Bs[3][BN * BK];
  const int t = threadIdx.x;
  const int l = t & 63;
  const int w = t >> 6;
  const int wr = w / WC, wc = w % WC;
  const int lr = l & 15, lg = l >> 4;

  const int gx = gridDim.x, gy = gridDim.y;
  const int nxy = gx * gy;
  const int flat = blockIdx.x * gy + blockIdx.y;
  const int nf = (flat & 7) * (nxy >> 3) + (flat >> 3);
  const int bx = nf / gy, by = nf % gy;

  const int m0 = by * BM, n0 = bx * BN;
  const int koff = blockIdx.z * kstep;
  A += koff; B += koff;
  Cf += (size_t)blockIdx.z * M * N;

  auto stage = [&](int b, int k0) {
#pragma unroll
    for (int i = 0; i < ACH; ++i) {
      const int ci = i * THREADS + t;
      const int r = ci >> 3, c = ci & 7;
      const int cs = c ^ (r & 7);
      gload_lds16(A + (size_t)(m0 + r) * lda + k0 + cs * 8,
                  &As[b][(size_t)(i * THREADS + w * 64) * 8]);
    }
#pragma unroll
    for (int i = 0; i < BCH; ++i) {
      const int ci = i * THREADS + t;
      const int r = ci >> 3, c = ci & 7;
      const int cs = c ^ (r & 7);
      gload_lds16(B + (size_t)(n0 + r) * ldb + k0 + cs * 8,
                  &Bs[b][(size_t)(i * THREADS + w * 64) * 8]);
    }
  };

  f32x4 acc[MR][NR] = {};
  const int nIter = K / BK;
  stage(0, 0);
  if (1 < nIter) stage(1, BK);
  for (int it = 0; it < nIter; ++it) {
    const int cur = it % 3;
    if (it + 1 < nIter) {
      static_assert(LPS == 6, "vmcnt literal assumes 6 loads/stage");
      asm volatile("s_waitcnt vmcnt(6)" ::: "memory");
    } else {
      asm volatile("s_waitcnt vmcnt(0)" ::: "memory");
    }
    __builtin_amdgcn_sched_barrier(0);
    __builtin_amdgcn_s_barrier();
    __builtin_amdgcn_sched_barrier(0);
#pragma unroll
    for (int kk = 0; kk < 2; ++kk) {
      short8 a[MR], b[NR];
#pragma unroll
      for (int m = 0; m < MR; ++m) {
        const int r = wr * (BM / WR) + m * 16 + lr;
        a[m] = *(const short8*)(&As[cur][r * BK + (((kk * 4 + lg) ^ (r & 7)) * 8)]);
      }
#pragma unroll
      for (int n = 0; n < NR; ++n) {
        const int r = wc * (BN / WC) + n * 16 + lr;
        b[n] = *(const short8*)(&Bs[cur][r * BK + (((kk * 4 + lg) ^ (r & 7)) * 8)]);
      }
#pragma unroll
      for (int m = 0; m < MR; ++m)
#pragma unroll
        for (int n = 0; n < NR; ++n)
          acc[m][n] = __builtin_amdgcn_mfma_f32_16x16x32_bf16(a[m], b[n], acc[m][n], 0, 0, 0);
    }
    if (it + 2 < nIter) stage((it + 2) % 3, (it + 2) * BK);
  }
#pragma unroll
  for (int n = 0; n < NR; ++n) {
    const int col = n0 + wc * (BN / WC) + n * 16 + lr;
    const float bv = BIAS ? bias[col] : 0.0f;
#pragma unroll
    for (int m = 0; m < MR; ++m) {
#pragma unroll
      for (int r = 0; r < 4; ++r) {
        const int row = m0 + wr * (BM / WR) + m * 16 + lg * 4 + r;
        float v = acc[m][n][r] + bv;
        if (RELU) v = fmaxf(v, 0.0f);
        if (BF16OUT) Cb[(size_t)row * N + col] = f2b(v);
        else         Cf[(size_t)row * N + col] = v;
      }
    }
  }
}

// ---------------- transpose V: qkvb[:,1024:2048] ([N][D]) -> vt [D][N] ----------------
__global__ void transpose_v(const short* __restrict__ src, short* __restrict__ dst) {
  __shared__ short tile[64][65];
  const int bx = blockIdx.x * 64;  // d
  const int by = blockIdx.y * 64;  // n
  const int t = threadIdx.x;
  const int tx = t & 63, ty = t >> 6;
#pragma unroll
  for (int i = 0; i < 64; i += 4)
    tile[ty + i][tx] = src[(size_t)(by + ty + i) * 2048 + 1024 + bx + tx];
  __syncthreads();
#pragma unroll
  for (int i = 0; i < 64; i += 4)
    dst[(size_t)(bx + ty + i) * 2048 + by + tx] = tile[tx][ty + i];
}

// ---------------- flash attention: QBLK=128, 32 Q-rows/wave (2 groups) ----------------
// grid (N/128, H); 256 threads. Wave w owns Q rows qb*128 + w*32 + g*16 (g=0,1).
// K/V tiles staged in LDS as before; kf/vf LDS reads are shared by both Q-groups
// (each fragment read feeds 2 MFMAs) -> LDS bytes per Q-row halved vs R9.
__launch_bounds__(256, 2)
__global__ void flash_attn(const short* __restrict__ qk, const short* __restrict__ vt,
                           float* __restrict__ O) {
  const int t = threadIdx.x;
  const int l = t & 63, w = t >> 6;
  const int lr = l & 15, lg = l >> 4;
  const int h = blockIdx.y;
  const int qb = blockIdx.x;
  __shared__ short Ks[2][64 * 64];
  __shared__ short Vs[2][64 * 64];
  __shared__ short Pl[4][2][16][72];
  const float C2 = 0.18033688011112042f;  // (1/sqrt(64)) * log2(e)

  // Q fragments: 2 groups of 16 rows
  short8 aq[2][2];
#pragma unroll
  for (int g = 0; g < 2; ++g) {
    const int qrow = qb * 128 + w * 32 + g * 16 + lr;
#pragma unroll
    for (int f = 0; f < 2; ++f)
      aq[g][f] = *(const short8*)(qk + (size_t)qrow * 2048 + h * 64 + f * 32 + lg * 8);
  }

  f32x4 o[2][4] = {};
  float mrun[2] = {-1e30f, -1e30f}, lrun[2] = {0.0f, 0.0f};

  auto stage = [&](int b, int kt) {
#pragma unroll
    for (int i = 0; i < 2; ++i) {
      const int chunk = i * 256 + w * 64 + l;
      const int r = chunk >> 3, c = chunk & 7;
      const int cs = c ^ (r & 7);
      gload_lds16(qk + (size_t)(kt * 64 + r) * 2048 + h * 64 + cs * 8,
                  &Ks[b][(size_t)(i * 256 + w * 64) * 8]);
    }
#pragma unroll
    for (int i = 0; i < 2; ++i) {
      const int chunk = i * 256 + w * 64 + l;
      const int r = chunk >> 3, c = chunk & 7;
      const int cs = c ^ (r & 7);
      gload_lds16(vt + (size_t)(h * 64 + r) * 2048 + kt * 64 + cs * 8,
                  &Vs[b][(size_t)(i * 256 + w * 64) * 8]);
    }
  };

  stage(0, 0);
  __syncthreads();

#pragma unroll 1
  for (int kt = 0; kt < 32; ++kt) {
    const int cur = kt & 1;
    if (kt + 1 < 32) stage(cur ^ 1, kt + 1);

    // QK^T (swapped): one kf read feeds both Q-groups
    f32x4 s[2][4] = {};
    __builtin_amdgcn_s_setprio(1);
#pragma unroll
    for (int f = 0; f < 2; ++f) {
      short8 kf[4];
#pragma unroll
      for (int n = 0; n < 4; ++n) {
        const int r = n * 16 + lr;
        kf[n] = *(const short8*)(&Ks[cur][r * 64 + (((f * 4 + lg) ^ (lr & 7)) * 8)]);
      }
#pragma unroll
      for (int g = 0; g < 2; ++g)
#pragma unroll
        for (int n = 0; n < 4; ++n)
          s[g][n] = __builtin_amdgcn_mfma_f32_16x16x32_bf16(kf[n], aq[g][f], s[g][n], 0, 0, 0);
    }
    __builtin_amdgcn_s_setprio(0);

    // softmax per group (lane holds Q-row (g,lr), K-positions n*16+lg*4+r)
#pragma unroll
    for (int g = 0; g < 2; ++g) {
      float m0 = fmaxf(fmaxf(s[g][0][0], s[g][0][1]), fmaxf(s[g][0][2], s[g][0][3]));
      float m1 = fmaxf(fmaxf(s[g][1][0], s[g][1][1]), fmaxf(s[g][1][2], s[g][1][3]));
      float m2 = fmaxf(fmaxf(s[g][2][0], s[g][2][1]), fmaxf(s[g][2][2], s[g][2][3]));
      float m3 = fmaxf(fmaxf(s[g][3][0], s[g][3][1]), fmaxf(s[g][3][2], s[g][3][3]));
      float tm = fmaxf(fmaxf(m0, m1), fmaxf(m2, m3));
      tm = fmaxf(tm, __shfl_xor(tm, 16));
      tm = fmaxf(tm, __shfl_xor(tm, 32));
      float corrv = 1.0f;
      if (__any(tm > mrun[g])) {
        const float mnew = fmaxf(mrun[g], tm);
        corrv = fexp2((mrun[g] - mnew) * C2);
        mrun[g] = mnew;
        f32x4 cov;
#pragma unroll
        for (int r = 0; r < 4; ++r)
          cov[r] = __shfl(corrv, lg * 4 + r);
#pragma unroll
        for (int n = 0; n < 4; ++n)
          o[g][n] *= cov;
      }
      float p[4][4];
#pragma unroll
      for (int n = 0; n < 4; ++n)
#pragma unroll
        for (int r = 0; r < 4; ++r)
          p[n][r] = fexp2((s[g][n][r] - mrun[g]) * C2);
      float q0 = (p[0][0] + p[0][1]) + (p[0][2] + p[0][3]);
      float q1 = (p[1][0] + p[1][1]) + (p[1][2] + p[1][3]);
      float q2 = (p[2][0] + p[2][1]) + (p[2][2] + p[2][3]);
      float q3 = (p[3][0] + p[3][1]) + (p[3][2] + p[3][3]);
      float ps = (q0 + q1) + (q2 + q3);
      ps += __shfl_xor(ps, 16);
      ps += __shfl_xor(ps, 32);
      lrun[g] = lrun[g] * corrv + ps;
#pragma unroll
      for (int n = 0; n < 4; ++n) {
        uint2 wv;
        wv.x = ((unsigned)(unsigned short)f2b(p[n][1]) << 16) | (unsigned short)f2b(p[n][0]);
        wv.y = ((unsigned)(unsigned short)f2b(p[n][3]) << 16) | (unsigned short)f2b(p[n][2]);
        *(uint2*)&Pl[w][g][lr][n * 16 + lg * 4] = wv;
      }
    }

    // PV: one vf read feeds both Q-groups
    __builtin_amdgcn_s_setprio(1);
#pragma unroll
    for (int f = 0; f < 2; ++f) {
      short8 ap0 = *(const short8*)&Pl[w][0][lr][f * 32 + lg * 8];
      short8 ap1 = *(const short8*)&Pl[w][1][lr][f * 32 + lg * 8];
      short8 vf[4];
#pragma unroll
      for (int n = 0; n < 4; ++n) {
        const int r = n * 16 + lr;
        vf[n] = *(const short8*)(&Vs[cur][r * 64 + (((f * 4 + lg) ^ (lr & 7)) * 8)]);
      }
#pragma unroll
      for (int n = 0; n < 4; ++n) {
        o[0][n] = __builtin_amdgcn_mfma_f32_16x16x32_bf16(ap0, vf[n], o[0][n], 0, 0, 0);
        o[1][n] = __builtin_amdgcn_mfma_f32_16x16x32_bf16(ap1, vf[n], o[1][n], 0, 0, 0);
      }
    }
    __builtin_amdgcn_s_setprio(0);
    __syncthreads();
  }

#pragma unroll
  for (int g = 0; g < 2; ++g) {
    f32x4 inv;
#pragma unroll
    for (int r = 0; r < 4; ++r)
      inv[r] = 1.0f / __shfl(lrun[g], lg * 4 + r);
#pragma unroll
    for (int n = 0; n < 4; ++n)
#pragma unroll
      for (int r = 0; r < 4; ++r)
        O[(size_t)(qb * 128 + w * 32 + g * 16 + lg * 4 + r) * 1024 + h * 64 + n * 16 + lr] =
            o[g][n][r] * inv[r];
  }
}

// ---------------- out = LN(A + B0 [+ B1] [+ bias]) * g + be ----------------
__launch_bounds__(256)
__global__ void add_ln(const float* __restrict__ A, const float* __restrict__ B0,
                       const float* __restrict__ B1, const float* __restrict__ bias,
                       const float* __restrict__ g, const float* __restrict__ be,
                       float* __restrict__ outf, short* __restrict__ outb) {
  const int row = blockIdx.x;
  const int t = threadIdx.x;
  const size_t base = (size_t)row * 1024 + t * 4;
  float4 a = *(const float4*)(A + base);
  float4 b = *(const float4*)(B0 + base);
  float4 s; s.x = a.x + b.x; s.y = a.y + b.y; s.z = a.z + b.z; s.w = a.w + b.w;
  if (B1) {
    float4 c = *(const float4*)(B1 + base);
    s.x += c.x; s.y += c.y; s.z += c.z; s.w += c.w;
  }
  if (bias) {
    float4 c = *(const float4*)(bias + t * 4);
    s.x += c.x; s.y += c.y; s.z += c.z; s.w += c.w;
  }
  float sum = s.x + s.y + s.z + s.w;
  float sq  = s.x * s.x + s.y * s.y + s.z * s.z + s.w * s.w;
#pragma unroll
  for (int d = 32; d > 0; d >>= 1) {
    sum += __shfl_down(sum, d);
    sq  += __shfl_down(sq, d);
  }
  __shared__ float red[8];
  const int w = t >> 6, l = t & 63;
  if (l == 0) { red[w] = sum; red[4 + w] = sq; }
  __syncthreads();
  sum = red[0] + red[1] + red[2] + red[3];
  sq  = red[4] + red[5] + red[6] + red[7];
  const float mu = sum * (1.0f / 1024.0f);
  const float rstd = rsqrtf(sq * (1.0f / 1024.0f) - mu * mu + 1e-5f);
  float4 gv = *(const float4*)(g + t * 4);
  float4 bv = *(const float4*)(be + t * 4);
  float4 o;
  o.x = (s.x - mu) * rstd * gv.x + bv.x;
  o.y = (s.y - mu) * rstd * gv.y + bv.y;
  o.z = (s.z - mu) * rstd * gv.z + bv.z;
  o.w = (s.w - mu) * rstd * gv.w + bv.w;
  *(float4*)(outf + base) = o;
  if (outb) {
    short4v ob; ob.x = f2b(o.x); ob.y = f2b(o.y); ob.z = f2b(o.z); ob.w = f2b(o.w);
    *(short4v*)(outb + base) = ob;
  }
}

extern "C" void kernel_launch(void* const* d_in, const int* in_sizes, int n_in,
                              void* d_out, int out_size, void* d_ws, size_t ws_size,
                              hipStream_t stream) {
  const float* X    = (const float*)d_in[0];
  const float* Wqkv = (const float*)d_in[1];
  const float* W1   = (const float*)d_in[2];
  const float* b1   = (const float*)d_in[3];
  const float* W2   = (const float*)d_in[4];
  const float* b2   = (const float*)d_in[5];
  const float* g1   = (const float*)d_in[6];
  const float* be1  = (const float*)d_in[7];
  const float* g2   = (const float*)d_in[8];
  const float* be2  = (const float*)d_in[9];

  // workspace, explicit offsets (60 MiB peak) — unchanged from R7-R9.
  char* ws = (char*)d_ws;
  const size_t MiB = 1u << 20;
  short*  W1b   = (short*)(ws + 0 * MiB);
  short*  W2b   = (short*)(ws + 8 * MiB);
  float*  h     = (float*)(ws + 16 * MiB);
  short*  hb    = (short*)(ws + 24 * MiB);
  short*  qkvb  = (short*)(ws + 28 * MiB);
  short*  y1b   = (short*)(ws + 28 * MiB);
  short*  vt    = (short*)(ws + 36 * MiB);
  float*  attn  = (float*)(ws + 44 * MiB);
  float*  P0    = (float*)(ws + 44 * MiB);
  float*  P1    = P0 + (size_t)NTOK * DMODEL;
  short*  Xb    = (short*)(ws + 52 * MiB);
  short*  Wqkvb = (short*)(ws + 56 * MiB);

  cast_all<<<6144, 256, 0, stream>>>(X, Xb, NTOK * DMODEL / 8,
                                     Wqkv, Wqkvb, 2 * DMODEL * DMODEL / 8,
                                     W1, W1b, DFF * DMODEL / 8,
                                     W2, W2b, DMODEL * DFF / 8);

  {  // qkv = X @ Wqkv^T -> bf16 [2048, 2048]; grid 512 (%8==0)
    dim3 grid(2 * DMODEL / 128, NTOK / 64, 1);
    gemm_bt<64, 128, 2, 2, true, false, false><<<grid, 256, 0, stream>>>(
        Xb, Wqkvb, nullptr, nullptr, qkvb, NTOK, 2 * DMODEL, DMODEL, DMODEL, DMODEL, 0);
  }
  {  // vt[d][n] = v[n][d]
    dim3 grid(DMODEL / 64, NTOK / 64);
    transpose_v<<<grid, 256, 0, stream>>>(qkvb, vt);
  }
  {  // attn_out f32 [2048, 1024]; QBLK=128 -> grid 256
    dim3 grid(NTOK / 128, NHEAD);
    flash_attn<<<grid, 256, 0, stream>>>(qkvb, vt, attn);
  }
  add_ln<<<NTOK, 256, 0, stream>>>(X, attn, nullptr, nullptr, g1, be1, h, hb);
  {  // y1 = relu(h @ W1^T + b1) -> bf16 [2048, 4096]; grid 1024
    dim3 grid(DFF / 128, NTOK / 64, 1);
    gemm_bt<64, 128, 2, 2, true, true, true><<<grid, 256, 0, stream>>>(
        hb, W1b, b1, nullptr, y1b, NTOK, DFF, DMODEL, DMODEL, DMODEL, 0);
  }
  {  // ffn2 partials: split-K=2; grid 256/z-slice (%8==0)
    dim3 grid(DMODEL / 128, NTOK / 64, 2);
    gemm_bt<64, 128, 2, 2, false, false, false><<<grid, 256, 0, stream>>>(
        y1b, W2b, nullptr, P0, nullptr, NTOK, DMODEL, 2048, DFF, DFF, 2048);
  }
  add_ln<<<NTOK, 256, 0, stream>>>(h, P0, P1, b2, g2, be2, (float*)d_out, nullptr);
}

// Round 11
// 233.470 us; speedup vs baseline: 1.0599x; 1.0599x over previous
//
#include <hip/hip_runtime.h>
#include <stdint.h>

// TransformerBlock on MI355X (gfx950), bf16-MFMA. Round 11.
// vs R10: flash reverted to R9 structure (QBLK=64, 512 blocks, 2 blocks/CU —
// R10's QBLK=128 lost block-level overlap and regressed). Added head-grouped
// bijective XCD swizzle in flash (each XCD owns 2 heads -> 1MB K/V L2-resident,
// FETCH 33.8MB -> ~15MB). GEMM/cast/LN/transpose unchanged from R9.

#define NTOK 2048
#define DMODEL 1024
#define NHEAD 16
#define DHEAD 64
#define DFF 4096

typedef __attribute__((ext_vector_type(8))) short short8;
typedef __attribute__((ext_vector_type(4))) short short4v;
typedef __attribute__((ext_vector_type(4))) float f32x4;

__device__ __forceinline__ float fexp2(float x) { return __builtin_amdgcn_exp2f(x); }

// fp32 -> bf16 RNE
__device__ __forceinline__ short f2b(float f) {
  union { float f; unsigned u; } v; v.f = f;
  unsigned r = v.u + 0x7fffu + ((v.u >> 16) & 1u);
  return (short)(r >> 16);
}

__device__ __forceinline__ void gload_lds16(const void* g, void* l) {
  __builtin_amdgcn_global_load_lds((const __attribute__((address_space(1))) void*)g,
                                   (__attribute__((address_space(3))) void*)l,
                                   16, 0, 0);
}

// ---------------- fused cast fp32 -> bf16 for 4 tensors ----------------
__global__ void cast_all(const float* __restrict__ s0, short* __restrict__ d0, int n0,
                         const float* __restrict__ s1, short* __restrict__ d1, int n1,
                         const float* __restrict__ s2, short* __restrict__ d2, int n2,
                         const float* __restrict__ s3, short* __restrict__ d3, int n3) {
  int i = blockIdx.x * blockDim.x + threadIdx.x;
  const float* s; short* d; int j = i;
  if (j < n0) { s = s0; d = d0; }
  else { j -= n0;
    if (j < n1) { s = s1; d = d1; }
    else { j -= n1;
      if (j < n2) { s = s2; d = d2; }
      else { j -= n2; if (j >= n3) return; s = s3; d = d3; }
    }
  }
  const float4* p = (const float4*)(s + (size_t)j * 8);
  float4 a = p[0], b = p[1];
  short8 o;
  o[0] = f2b(a.x); o[1] = f2b(a.y); o[2] = f2b(a.z); o[3] = f2b(a.w);
  o[4] = f2b(b.x); o[5] = f2b(b.y); o[6] = f2b(b.z); o[7] = f2b(b.w);
  *(short8*)(d + (size_t)j * 8) = o;
}

// ---------------- GEMM: C = A @ B^T (+relu/bias), bf16 in, f32 acc (R9) ----------------
template<int BM, int BN, int WR, int WC, bool BF16OUT, bool BIAS, bool RELU>
__launch_bounds__(WR * WC * 64, 2)
__global__ void gemm_bt(const short* __restrict__ A, const short* __restrict__ B,
                        const float* __restrict__ bias,
                        float* __restrict__ Cf, short* __restrict__ Cb,
                        int M, int N, int K, int lda, int ldb, int kstep) {
  constexpr int BK = 64;
  constexpr int THREADS = WR * WC * 64;
  constexpr int ACH = (BM * (BK / 8)) / THREADS;
  constexpr int BCH = (BN * (BK / 8)) / THREADS;
  constexpr int LPS = ACH + BCH;
  constexpr int MR = BM / (WR * 16);
  constexpr int NR = BN / (WC * 16);
  __shared__ short As[3][BM * BK];
  __shared__ short Bs[3][BN * BK];
  const int t = threadIdx.x;
  const int l = t & 63;
  const int w = t >> 6;
  const int wr = w / WC, wc = w % WC;
  const int lr = l & 15, lg = l >> 4;

  const int gx = gridDim.x, gy = gridDim.y;
  const int nxy = gx * gy;
  const int flat = blockIdx.x * gy + blockIdx.y;
  const int nf = (flat & 7) * (nxy >> 3) + (flat >> 3);
  const int bx = nf / gy, by = nf % gy;

  const int m0 = by * BM, n0 = bx * BN;
  const int koff = blockIdx.z * kstep;
  A += koff; B += koff;
  Cf += (size_t)blockIdx.z * M * N;

  auto stage = [&](int b, int k0) {
#pragma unroll
    for (int i = 0; i < ACH; ++i) {
      const int ci = i * THREADS + t;
      const int r = ci >> 3, c = ci & 7;
      const int cs = c ^ (r & 7);
      gload_lds16(A + (size_t)(m0 + r) * lda + k0 + cs * 8,
                  &As[b][(size_t)(i * THREADS + w * 64) * 8]);
    }
#pragma unroll
    for (int i = 0; i < BCH; ++i) {
      const int ci = i * THREADS + t;
      const int r = ci >> 3, c = ci & 7;
      const int cs = c ^ (r & 7);
      gload_lds16(B + (size_t)(n0 + r) * ldb + k0 + cs * 8,
                  &Bs[b][(size_t)(i * THREADS + w * 64) * 8]);
    }
  };

  f32x4 acc[MR][NR] = {};
  const int nIter = K / BK;
  stage(0, 0);
  if (1 < nIter) stage(1, BK);
  for (int it = 0; it < nIter; ++it) {
    const int cur = it % 3;
    if (it + 1 < nIter) {
      static_assert(LPS == 6, "vmcnt literal assumes 6 loads/stage");
      asm volatile("s_waitcnt vmcnt(6)" ::: "memory");
    } else {
      asm volatile("s_waitcnt vmcnt(0)" ::: "memory");
    }
    __builtin_amdgcn_sched_barrier(0);
    __builtin_amdgcn_s_barrier();
    __builtin_amdgcn_sched_barrier(0);
#pragma unroll
    for (int kk = 0; kk < 2; ++kk) {
      short8 a[MR], b[NR];
#pragma unroll
      for (int m = 0; m < MR; ++m) {
        const int r = wr * (BM / WR) + m * 16 + lr;
        a[m] = *(const short8*)(&As[cur][r * BK + (((kk * 4 + lg) ^ (r & 7)) * 8)]);
      }
#pragma unroll
      for (int n = 0; n < NR; ++n) {
        const int r = wc * (BN / WC) + n * 16 + lr;
        b[n] = *(const short8*)(&Bs[cur][r * BK + (((kk * 4 + lg) ^ (r & 7)) * 8)]);
      }
#pragma unroll
      for (int m = 0; m < MR; ++m)
#pragma unroll
        for (int n = 0; n < NR; ++n)
          acc[m][n] = __builtin_amdgcn_mfma_f32_16x16x32_bf16(a[m], b[n], acc[m][n], 0, 0, 0);
    }
    if (it + 2 < nIter) stage((it + 2) % 3, (it + 2) * BK);
  }
#pragma unroll
  for (int n = 0; n < NR; ++n) {
    const int col = n0 + wc * (BN / WC) + n * 16 + lr;
    const float bv = BIAS ? bias[col] : 0.0f;
#pragma unroll
    for (int m = 0; m < MR; ++m) {
#pragma unroll
      for (int r = 0; r < 4; ++r) {
        const int row = m0 + wr * (BM / WR) + m * 16 + lg * 4 + r;
        float v = acc[m][n][r] + bv;
        if (RELU) v = fmaxf(v, 0.0f);
        if (BF16OUT) Cb[(size_t)row * N + col] = f2b(v);
        else         Cf[(size_t)row * N + col] = v;
      }
    }
  }
}

// ---------------- transpose V: qkvb[:,1024:2048] ([N][D]) -> vt [D][N] ----------------
__global__ void transpose_v(const short* __restrict__ src, short* __restrict__ dst) {
  __shared__ short tile[64][65];
  const int bx = blockIdx.x * 64;  // d
  const int by = blockIdx.y * 64;  // n
  const int t = threadIdx.x;
  const int tx = t & 63, ty = t >> 6;
#pragma unroll
  for (int i = 0; i < 64; i += 4)
    tile[ty + i][tx] = src[(size_t)(by + ty + i) * 2048 + 1024 + bx + tx];
  __syncthreads();
#pragma unroll
  for (int i = 0; i < 64; i += 4)
    dst[(size_t)(bx + ty + i) * 2048 + by + tx] = tile[tx][ty + i];
}

// ---------------- flash attention, LDS-staged K/V, 4 waves/block (R9 + XCD head swizzle) ----------------
// grid 512 blocks; bijective remap nf = (flat&7)*64 + flat>>3 gives each XCD a
// contiguous nf range -> 2 heads (h = nf>>5), K/V working set 1MB, L2-resident.
__launch_bounds__(256, 2)
__global__ void flash_attn(const short* __restrict__ qk, const short* __restrict__ vt,
                           float* __restrict__ O) {
  const int t = threadIdx.x;
  const int l = t & 63, w = t >> 6;
  const int lr = l & 15, lg = l >> 4;
  const int flat = blockIdx.y * gridDim.x + blockIdx.x;  // x fastest in dispatch
  const int nf = (flat & 7) * 64 + (flat >> 3);          // 512 blocks: bijective
  const int h = nf >> 5;                                 // 2 heads per XCD
  const int qb = nf & 31;
  __shared__ short Ks[2][64 * 64];
  __shared__ short Vs[2][64 * 64];
  __shared__ short Pl[4][16][72];
  const float C2 = 0.18033688011112042f;  // (1/sqrt(64)) * log2(e)

  const int qrow = qb * 64 + w * 16 + lr;
  short8 aq[2];
#pragma unroll
  for (int f = 0; f < 2; ++f)
    aq[f] = *(const short8*)(qk + (size_t)qrow * 2048 + h * 64 + f * 32 + lg * 8);

  f32x4 o[4] = {};
  float mrun = -1e30f, lrun = 0.0f;

  auto stage = [&](int b, int kt) {
#pragma unroll
    for (int i = 0; i < 2; ++i) {
      const int chunk = i * 256 + w * 64 + l;
      const int r = chunk >> 3, c = chunk & 7;
      const int cs = c ^ (r & 7);
      gload_lds16(qk + (size_t)(kt * 64 + r) * 2048 + h * 64 + cs * 8,
                  &Ks[b][(size_t)(i * 256 + w * 64) * 8]);
    }
#pragma unroll
    for (int i = 0; i < 2; ++i) {
      const int chunk = i * 256 + w * 64 + l;
      const int r = chunk >> 3, c = chunk & 7;
      const int cs = c ^ (r & 7);
      gload_lds16(vt + (size_t)(h * 64 + r) * 2048 + kt * 64 + cs * 8,
                  &Vs[b][(size_t)(i * 256 + w * 64) * 8]);
    }
  };

  stage(0, 0);
  __syncthreads();

#pragma unroll 1
  for (int kt = 0; kt < 32; ++kt) {
    const int cur = kt & 1;
    if (kt + 1 < 32) stage(cur ^ 1, kt + 1);

    f32x4 s[4] = {};
    __builtin_amdgcn_s_setprio(1);
#pragma unroll
    for (int f = 0; f < 2; ++f) {
      short8 kf[4];
#pragma unroll
      for (int n = 0; n < 4; ++n) {
        const int r = n * 16 + lr;
        kf[n] = *(const short8*)(&Ks[cur][r * 64 + (((f * 4 + lg) ^ (lr & 7)) * 8)]);
      }
#pragma unroll
      for (int n = 0; n < 4; ++n)
        s[n] = __builtin_amdgcn_mfma_f32_16x16x32_bf16(kf[n], aq[f], s[n], 0, 0, 0);
    }
    __builtin_amdgcn_s_setprio(0);
    float m0 = fmaxf(fmaxf(s[0][0], s[0][1]), fmaxf(s[0][2], s[0][3]));
    float m1 = fmaxf(fmaxf(s[1][0], s[1][1]), fmaxf(s[1][2], s[1][3]));
    float m2 = fmaxf(fmaxf(s[2][0], s[2][1]), fmaxf(s[2][2], s[2][3]));
    float m3 = fmaxf(fmaxf(s[3][0], s[3][1]), fmaxf(s[3][2], s[3][3]));
    float tm = fmaxf(fmaxf(m0, m1), fmaxf(m2, m3));
    tm = fmaxf(tm, __shfl_xor(tm, 16));
    tm = fmaxf(tm, __shfl_xor(tm, 32));
    float corrv = 1.0f;
    if (__any(tm > mrun)) {
      const float mnew = fmaxf(mrun, tm);
      corrv = fexp2((mrun - mnew) * C2);
      mrun = mnew;
      f32x4 cov;
#pragma unroll
      for (int r = 0; r < 4; ++r)
        cov[r] = __shfl(corrv, lg * 4 + r);
#pragma unroll
      for (int n = 0; n < 4; ++n)
        o[n] *= cov;
    }
    float p[4][4];
#pragma unroll
    for (int n = 0; n < 4; ++n)
#pragma unroll
      for (int r = 0; r < 4; ++r)
        p[n][r] = fexp2((s[n][r] - mrun) * C2);
    float q0 = (p[0][0] + p[0][1]) + (p[0][2] + p[0][3]);
    float q1 = (p[1][0] + p[1][1]) + (p[1][2] + p[1][3]);
    float q2 = (p[2][0] + p[2][1]) + (p[2][2] + p[2][3]);
    float q3 = (p[3][0] + p[3][1]) + (p[3][2] + p[3][3]);
    float ps = (q0 + q1) + (q2 + q3);
    ps += __shfl_xor(ps, 16);
    ps += __shfl_xor(ps, 32);
    lrun = lrun * corrv + ps;
#pragma unroll
    for (int n = 0; n < 4; ++n) {
      uint2 wv;
      wv.x = ((unsigned)(unsigned short)f2b(p[n][1]) << 16) | (unsigned short)f2b(p[n][0]);
      wv.y = ((unsigned)(unsigned short)f2b(p[n][3]) << 16) | (unsigned short)f2b(p[n][2]);
      *(uint2*)&Pl[w][lr][n * 16 + lg * 4] = wv;
    }
    __builtin_amdgcn_s_setprio(1);
#pragma unroll
    for (int f = 0; f < 2; ++f) {
      short8 ap = *(const short8*)&Pl[w][lr][f * 32 + lg * 8];
      short8 vf[4];
#pragma unroll
      for (int n = 0; n < 4; ++n) {
        const int r = n * 16 + lr;
        vf[n] = *(const short8*)(&Vs[cur][r * 64 + (((f * 4 + lg) ^ (lr & 7)) * 8)]);
      }
#pragma unroll
      for (int n = 0; n < 4; ++n)
        o[n] = __builtin_amdgcn_mfma_f32_16x16x32_bf16(ap, vf[n], o[n], 0, 0, 0);
    }
    __builtin_amdgcn_s_setprio(0);
    __syncthreads();
  }

  f32x4 inv;
#pragma unroll
  for (int r = 0; r < 4; ++r)
    inv[r] = 1.0f / __shfl(lrun, lg * 4 + r);
#pragma unroll
  for (int n = 0; n < 4; ++n)
#pragma unroll
    for (int r = 0; r < 4; ++r)
      O[(size_t)(qb * 64 + w * 16 + lg * 4 + r) * 1024 + h * 64 + n * 16 + lr] = o[n][r] * inv[r];
}

// ---------------- out = LN(A + B0 [+ B1] [+ bias]) * g + be ----------------
__launch_bounds__(256)
__global__ void add_ln(const float* __restrict__ A, const float* __restrict__ B0,
                       const float* __restrict__ B1, const float* __restrict__ bias,
                       const float* __restrict__ g, const float* __restrict__ be,
                       float* __restrict__ outf, short* __restrict__ outb) {
  const int row = blockIdx.x;
  const int t = threadIdx.x;
  const size_t base = (size_t)row * 1024 + t * 4;
  float4 a = *(const float4*)(A + base);
  float4 b = *(const float4*)(B0 + base);
  float4 s; s.x = a.x + b.x; s.y = a.y + b.y; s.z = a.z + b.z; s.w = a.w + b.w;
  if (B1) {
    float4 c = *(const float4*)(B1 + base);
    s.x += c.x; s.y += c.y; s.z += c.z; s.w += c.w;
  }
  if (bias) {
    float4 c = *(const float4*)(bias + t * 4);
    s.x += c.x; s.y += c.y; s.z += c.z; s.w += c.w;
  }
  float sum = s.x + s.y + s.z + s.w;
  float sq  = s.x * s.x + s.y * s.y + s.z * s.z + s.w * s.w;
#pragma unroll
  for (int d = 32; d > 0; d >>= 1) {
    sum += __shfl_down(sum, d);
    sq  += __shfl_down(sq, d);
  }
  __shared__ float red[8];
  const int w = t >> 6, l = t & 63;
  if (l == 0) { red[w] = sum; red[4 + w] = sq; }
  __syncthreads();
  sum = red[0] + red[1] + red[2] + red[3];
  sq  = red[4] + red[5] + red[6] + red[7];
  const float mu = sum * (1.0f / 1024.0f);
  const float rstd = rsqrtf(sq * (1.0f / 1024.0f) - mu * mu + 1e-5f);
  float4 gv = *(const float4*)(g + t * 4);
  float4 bv = *(const float4*)(be + t * 4);
  float4 o;
  o.x = (s.x - mu) * rstd * gv.x + bv.x;
  o.y = (s.y - mu) * rstd * gv.y + bv.y;
  o.z = (s.z - mu) * rstd * gv.z + bv.z;
  o.w = (s.w - mu) * rstd * gv.w + bv.w;
  *(float4*)(outf + base) = o;
  if (outb) {
    short4v ob; ob.x = f2b(o.x); ob.y = f2b(o.y); ob.z = f2b(o.z); ob.w = f2b(o.w);
    *(short4v*)(outb + base) = ob;
  }
}

extern "C" void kernel_launch(void* const* d_in, const int* in_sizes, int n_in,
                              void* d_out, int out_size, void* d_ws, size_t ws_size,
                              hipStream_t stream) {
  const float* X    = (const float*)d_in[0];
  const float* Wqkv = (const float*)d_in[1];
  const float* W1   = (const float*)d_in[2];
  const float* b1   = (const float*)d_in[3];
  const float* W2   = (const float*)d_in[4];
  const float* b2   = (const float*)d_in[5];
  const float* g1   = (const float*)d_in[6];
  const float* be1  = (const float*)d_in[7];
  const float* g2   = (const float*)d_in[8];
  const float* be2  = (const float*)d_in[9];

  // workspace, explicit offsets (60 MiB peak) — unchanged from R7-R10.
  char* ws = (char*)d_ws;
  const size_t MiB = 1u << 20;
  short*  W1b   = (short*)(ws + 0 * MiB);
  short*  W2b   = (short*)(ws + 8 * MiB);
  float*  h     = (float*)(ws + 16 * MiB);
  short*  hb    = (short*)(ws + 24 * MiB);
  short*  qkvb  = (short*)(ws + 28 * MiB);
  short*  y1b   = (short*)(ws + 28 * MiB);
  short*  vt    = (short*)(ws + 36 * MiB);
  float*  attn  = (float*)(ws + 44 * MiB);
  float*  P0    = (float*)(ws + 44 * MiB);
  float*  P1    = P0 + (size_t)NTOK * DMODEL;
  short*  Xb    = (short*)(ws + 52 * MiB);
  short*  Wqkvb = (short*)(ws + 56 * MiB);

  cast_all<<<6144, 256, 0, stream>>>(X, Xb, NTOK * DMODEL / 8,
                                     Wqkv, Wqkvb, 2 * DMODEL * DMODEL / 8,
                                     W1, W1b, DFF * DMODEL / 8,
                                     W2, W2b, DMODEL * DFF / 8);

  {  // qkv = X @ Wqkv^T -> bf16 [2048, 2048]; grid 512 (%8==0)
    dim3 grid(2 * DMODEL / 128, NTOK / 64, 1);
    gemm_bt<64, 128, 2, 2, true, false, false><<<grid, 256, 0, stream>>>(
        Xb, Wqkvb, nullptr, nullptr, qkvb, NTOK, 2 * DMODEL, DMODEL, DMODEL, DMODEL, 0);
  }
  {  // vt[d][n] = v[n][d]
    dim3 grid(DMODEL / 64, NTOK / 64);
    transpose_v<<<grid, 256, 0, stream>>>(qkvb, vt);
  }
  {  // attn_out f32 [2048, 1024]; QBLK=64 -> grid 512
    dim3 grid(NTOK / 64, NHEAD);
    flash_attn<<<grid, 256, 0, stream>>>(qkvb, vt, attn);
  }
  add_ln<<<NTOK, 256, 0, stream>>>(X, attn, nullptr, nullptr, g1, be1, h, hb);
  {  // y1 = relu(h @ W1^T + b1) -> bf16 [2048, 4096]; grid 1024
    dim3 grid(DFF / 128, NTOK / 64, 1);
    gemm_bt<64, 128, 2, 2, true, true, true><<<grid, 256, 0, stream>>>(
        hb, W1b, b1, nullptr, y1b, NTOK, DFF, DMODEL, DMODEL, DMODEL, 0);
  }
  {  // ffn2 partials: split-K=2; grid 256/z-slice (%8==0)
    dim3 grid(DMODEL / 128, NTOK / 64, 2);
    gemm_bt<64, 128, 2, 2, false, false, false><<<grid, 256, 0, stream>>>(
        y1b, W2b, nullptr, P0, nullptr, NTOK, DMODEL, 2048, DFF, DFF, 2048);
  }
  add_ln<<<NTOK, 256, 0, stream>>>(h, P0, P1, b2, g2, be2, (float*)d_out, nullptr);
}